// Round 13
// baseline (106.391 us; speedup 1.0000x reference)
//
#include <hip/hip_runtime.h>

#define BB 128
#define LL 336
#define CC 862
#define PRED 96
#define WIN 12
#define S_IN 28
#define S_OUT 8
#define CT 16
#define RS 340                         // padded LDS row stride (dwords)
#define NTILES ((CC + CT - 1) / CT)    // 54
#define SH 14                          // s per half

#define SQRT12F 3.4641016151377544f

// -Sb(t)/sqrt(12), Sb(t) = 2*sum_{k=1..5} sin(pi*k*t/6)   (exact closed forms)
__device__ const float COEFP[12] = {
    0.0f, -2.1547005383792515f, 0.0f, -0.5773502691896258f,
    0.0f, -0.15470053837925146f, 0.0f, 0.15470053837925146f,
    0.0f,  0.5773502691896258f, 0.0f,  2.1547005383792515f
};

// ---- prep kernels ----

// packed weights: wpk[((p*S_IN + s)*CC + c)*2 + {0,1}] = {wA, wP}[c][p][s]
__global__ void prep_wpk(const float* __restrict__ wA, const float* __restrict__ wP,
                         float* __restrict__ wpk) {
    int i = blockIdx.x * 256 + threadIdx.x;          // i = (p*S_IN + s)*CC + c
    if (i >= S_OUT * S_IN * CC) return;
    int c  = i % CC;
    int ps = i / CC;
    int s  = ps % S_IN;
    int p  = ps / S_IN;
    int src = (c * S_OUT + p) * S_IN + s;
    wpk[2 * i]     = wA[src];
    wpk[2 * i + 1] = wP[src];
}

__global__ void prep_mcoef(const float* __restrict__ wA, float* __restrict__ mcoefT) {
    int i = blockIdx.x * 256 + threadIdx.x;          // [p][c]
    if (i >= S_OUT * CC) return;
    int c = i % CC;
    int p = i / CC;
    float s = 0.f;
    for (int k = 0; k < S_IN; ++k) s += wA[(c * S_OUT + p) * S_IN + k];
    mcoefT[i] = 1.0f - s;
}

__global__ void prep_bias(const float* __restrict__ bA, const float* __restrict__ bP,
                          float* __restrict__ biasv) {
    int i = blockIdx.x * 256 + threadIdx.x;          // [t][p][c]
    if (i >= 12 * S_OUT * CC) return;
    int c = i % CC;
    int tp = i / CC;
    int p = tp % S_OUT;
    int t = tp / S_OUT;
    float v = COEFP[t] * bP[c * S_OUT + p];
    if (t == 0) v += SQRT12F * bA[c * S_OUT + p];
    biasv[i] = v;
}

// ---- fused main kernel ----
// CT=16 + s-split: thread = (cc 0..15, p 0..7, h 0..1); each half does 14 s.
// Small LDS (21.8 KB) + <=64 VGPR -> up to 7 blocks/CU: block phases interleave,
// keeping many staging waves in flight (the r4..r12 plateau was phase-serialization).
// Reduction buffer overlaid on the dead x tile after a sync.

template <bool TRANS>
__global__ __launch_bounds__(256, 8) void fused13(
    const float* __restrict__ x,
    const float* __restrict__ wpk,
    const float* __restrict__ mcoefT, const float* __restrict__ biasv,
    const float* __restrict__ wA_raw, const float* __restrict__ wP_raw,
    const float* __restrict__ bAr, const float* __restrict__ bPr,
    float* __restrict__ out)
{
    __shared__ __align__(16) float sxT[CT * RS];   // 21760 B (reused as red buf)

    const int b   = blockIdx.y;
    const int c0  = blockIdx.x * CT;
    const int NC  = min(CT, CC - c0);   // 16 or 14 (always even)
    const int tid = threadIdx.x;

    // ---- stage x[b, :, c0:c0+NC] transposed (float2 global, b32 LDS scatter) ----
    {
        const int slot = tid & 7;        // float2 slot (8 per row)
        const int r0   = tid >> 3;       // 0..31
        const int col  = 2 * slot;
        const int csrc = (col + 1 < NC) ? col : (NC - 2);
        const float* base = x + ((size_t)b * LL) * CC + c0 + csrc;
        float* d0 = sxT + col * RS;
        float* d1 = sxT + (col + 1) * RS;
        #pragma unroll
        for (int k = 0; k < 11; ++k) {
            const int r = r0 + 32 * k;
            if (r < LL) {
                const float2 v = *reinterpret_cast<const float2*>(base + (size_t)r * CC);
                d0[r] = v.x;
                d1[r] = v.y;
            }
        }
    }
    __syncthreads();

    const int cc = tid & 15;
    const int p  = (tid >> 4) & 7;
    const int h  = tid >> 7;             // 0 or 1
    const int c  = c0 + cc;
    const bool wrOK = (cc < NC);
    const int cl = wrOK ? c : (CC - 1);  // clamped for global loads

    float A0 = 0.f, A6 = 0.f;
    float Au[5] = {0.f, 0.f, 0.f, 0.f, 0.f};
    float Pv[5] = {0.f, 0.f, 0.f, 0.f, 0.f};
    float msum = 0.f;
    float sw = 0.f;                      // fallback only

    const float* xrow = sxT + cc * RS + 12 * (h * SH);
    const int s0 = h * SH;

    #pragma unroll 2
    for (int i = 0; i < SH; ++i) {
        const int s = s0 + i;
        float wa, wp;
        if (TRANS) {
            const float2 w = *reinterpret_cast<const float2*>(
                wpk + 2 * ((size_t)(p * S_IN + s) * CC + cl));
            wa = w.x; wp = w.y;
        } else {
            wa = wA_raw[(size_t)(cl * S_OUT + p) * S_IN + s];
            wp = wP_raw[(size_t)(cl * S_OUT + p) * S_IN + s];
            sw += wa;
        }
        const float4 xa = *reinterpret_cast<const float4*>(xrow + 12 * i);      // t0..3
        const float4 xb = *reinterpret_cast<const float4*>(xrow + 12 * i + 4);  // t4..7
        const float4 xc = *reinterpret_cast<const float4*>(xrow + 12 * i + 8);  // t8..11

        const float u1 = xa.y + xc.w;
        const float u2 = xa.z + xc.z;
        const float u3 = xa.w + xc.y;
        const float u4 = xb.x + xc.x;
        const float u5 = xb.y + xb.w;
        const float v1 = xa.y - xc.w;
        const float v2 = xa.z - xc.z;
        const float v3 = xa.w - xc.y;
        const float v4 = xb.x - xc.x;
        const float v5 = xb.y - xb.w;

        A0 = fmaf(wa, xa.x, A0);
        A6 = fmaf(wa, xb.z, A6);
        Au[0] = fmaf(wa, u1, Au[0]);
        Au[1] = fmaf(wa, u2, Au[1]);
        Au[2] = fmaf(wa, u3, Au[2]);
        Au[3] = fmaf(wa, u4, Au[3]);
        Au[4] = fmaf(wa, u5, Au[4]);
        Pv[0] = fmaf(wp, v1, Pv[0]);
        Pv[1] = fmaf(wp, v2, Pv[1]);
        Pv[2] = fmaf(wp, v3, Pv[2]);
        Pv[3] = fmaf(wp, v4, Pv[3]);
        Pv[4] = fmaf(wp, v5, Pv[4]);

        msum += (xa.x + xb.z) + ((u1 + u2) + (u3 + u4) + u5);
    }

    // ---- combine halves via LDS (overlaid on the dead x tile) ----
    __syncthreads();                     // all reads of sxT done
    float* red = sxT;                    // 128 * 14 floats = 7168 B
    if (h == 1) {
        float* r = red + (p * 16 + cc) * 14;
        r[0] = A0;  r[1] = A6;
        r[2] = Au[0]; r[3] = Au[1]; r[4] = Au[2]; r[5] = Au[3]; r[6] = Au[4];
        r[7] = Pv[0]; r[8] = Pv[1]; r[9] = Pv[2]; r[10] = Pv[3]; r[11] = Pv[4];
        r[12] = msum; r[13] = sw;
    }
    __syncthreads();
    if (h == 1) return;

    {
        const float* r = red + (p * 16 + cc) * 14;
        A0 += r[0];  A6 += r[1];
        Au[0] += r[2]; Au[1] += r[3]; Au[2] += r[4]; Au[3] += r[5]; Au[4] += r[6];
        Pv[0] += r[7]; Pv[1] += r[8]; Pv[2] += r[9]; Pv[3] += r[10]; Pv[4] += r[11];
        msum += r[12]; sw += r[13];
    }

    if (!wrOK) return;

    const float mean = msum * (1.0f / LL);

    float mc, bias[12];
    if (TRANS) {
        mc = mcoefT[p * CC + c];
        #pragma unroll
        for (int t = 0; t < 12; ++t) bias[t] = biasv[(size_t)(t * S_OUT + p) * CC + c];
    } else {
        mc = 1.0f - sw;
        const float ba = bAr[c * S_OUT + p], bp = bPr[c * S_OUT + p];
        #pragma unroll
        for (int t = 0; t < 12; ++t) {
            bias[t] = COEFP[t] * bp + (t == 0 ? SQRT12F * ba : 0.f);
        }
    }

    const float mb = mean * mc;
    float* ob = out + ((size_t)b * PRED + p * WIN) * CC + c;

    ob[0]               = A0 + mb + bias[0];
    ob[(size_t)6 * CC]  = A6 + mb + bias[6];
    #pragma unroll
    for (int t = 1; t <= 5; ++t) {
        ob[(size_t)t * CC]        = 0.5f * (Au[t-1] + Pv[t-1]) + mb + bias[t];
        ob[(size_t)(12 - t) * CC] = 0.5f * (Au[t-1] - Pv[t-1]) + mb + bias[12 - t];
    }
}

extern "C" void kernel_launch(void* const* d_in, const int* in_sizes, int n_in,
                              void* d_out, int out_size, void* d_ws, size_t ws_size,
                              hipStream_t stream) {
    const float* x  = (const float*)d_in[0];
    const float* wA = (const float*)d_in[1];
    const float* bA = (const float*)d_in[2];
    const float* wP = (const float*)d_in[3];
    const float* bP = (const float*)d_in[4];
    float* out = (float*)d_out;

    const size_t nW  = (size_t)S_OUT * S_IN * CC;    // 193088
    const size_t nM  = (size_t)S_OUT * CC;           // 6896
    const size_t nBv = (size_t)12 * S_OUT * CC;      // 82752
    const size_t need = (2 * nW + nM + nBv) * sizeof(float);

    dim3 grid(NTILES, BB);

    if (ws_size >= need) {
        float* wpk    = (float*)d_ws;                // 2*nW floats
        float* mcoefT = wpk + 2 * nW;
        float* biasv  = mcoefT + nM;

        prep_wpk<<<(int)((nW + 255) / 256), 256, 0, stream>>>(wA, wP, wpk);
        prep_mcoef<<<(int)((nM + 255) / 256), 256, 0, stream>>>(wA, mcoefT);
        prep_bias<<<(int)((nBv + 255) / 256), 256, 0, stream>>>(bA, bP, biasv);

        fused13<true><<<grid, 256, 0, stream>>>(
            x, wpk, mcoefT, biasv,
            nullptr, nullptr, nullptr, nullptr, out);
    } else {
        fused13<false><<<grid, 256, 0, stream>>>(
            x, nullptr, nullptr, nullptr,
            wA, wP, bA, bP, out);
    }
}

// Round 14
// 86.189 us; speedup vs baseline: 1.2344x; 1.2344x over previous
//
#include <hip/hip_runtime.h>

#define BB 128
#define LL 336
#define CC 862
#define PRED 96
#define WIN 12
#define S_IN 28
#define S_OUT 8
#define CT 32
#define RS 340                         // padded LDS row stride (dwords), mult of 4 for b128
#define NTILES ((CC + CT - 1) / CT)    // 27
#define SH 14                          // s per half

#define SQRT12F 3.4641016151377544f

// -Sb(t)/sqrt(12), Sb(t) = 2*sum_{k=1..5} sin(pi*k*t/6)   (exact closed forms)
__device__ const float COEFP[12] = {
    0.0f, -2.1547005383792515f, 0.0f, -0.5773502691896258f,
    0.0f, -0.15470053837925146f, 0.0f, 0.15470053837925146f,
    0.0f,  0.5773502691896258f, 0.0f,  2.1547005383792515f
};

// ---- prep kernels ----

// packed weights: wpk[((p*S_IN + s)*CC + c)*2 + {0,1}] = {wA, wP}[c][p][s]
__global__ void prep_wpk(const float* __restrict__ wA, const float* __restrict__ wP,
                         float* __restrict__ wpk) {
    int i = blockIdx.x * 256 + threadIdx.x;          // i = (p*S_IN + s)*CC + c
    if (i >= S_OUT * S_IN * CC) return;
    int c  = i % CC;
    int ps = i / CC;
    int s  = ps % S_IN;
    int p  = ps / S_IN;
    int src = (c * S_OUT + p) * S_IN + s;
    wpk[2 * i]     = wA[src];
    wpk[2 * i + 1] = wP[src];
}

__global__ void prep_mcoef(const float* __restrict__ wA, float* __restrict__ mcoefT) {
    int i = blockIdx.x * 256 + threadIdx.x;          // [p][c]
    if (i >= S_OUT * CC) return;
    int c = i % CC;
    int p = i / CC;
    float s = 0.f;
    for (int k = 0; k < S_IN; ++k) s += wA[(c * S_OUT + p) * S_IN + k];
    mcoefT[i] = 1.0f - s;
}

__global__ void prep_bias(const float* __restrict__ bA, const float* __restrict__ bP,
                          float* __restrict__ biasv) {
    int i = blockIdx.x * 256 + threadIdx.x;          // [t][p][c]
    if (i >= 12 * S_OUT * CC) return;
    int c = i % CC;
    int tp = i / CC;
    int p = tp % S_OUT;
    int t = tp / S_OUT;
    float v = COEFP[t] * bP[c * S_OUT + p];
    if (t == 0) v += SQRT12F * bA[c * S_OUT + p];
    biasv[i] = v;
}

// ---- fused main kernel ----
// CT=32 (128-B aligned traffic, r10/r12) + 512-thread blocks with s-split
// (r13's occupancy mechanism without its narrow-tile over-fetch).
// thread = (cc 0..31, p 0..7, h 0..1); each half does 14 s.
// LDS 43.5 KB/block -> 3 blocks/CU = 24 waves/CU if VGPR<=64
// (launch_bounds(512,8) caps at 64; identical body measured 36 in r13).

template <bool TRANS>
__global__ __launch_bounds__(512, 8) void fused14(
    const float* __restrict__ x,
    const float* __restrict__ wpk,
    const float* __restrict__ mcoefT, const float* __restrict__ biasv,
    const float* __restrict__ wA_raw, const float* __restrict__ wP_raw,
    const float* __restrict__ bAr, const float* __restrict__ bPr,
    float* __restrict__ out)
{
    __shared__ __align__(16) float sxT[CT * RS];   // 43520 B (reused as red buf)

    const int b   = blockIdx.y;
    const int c0  = blockIdx.x * CT;
    const int NC  = min(CT, CC - c0);   // 32 or 30 (always even)
    const int tid = threadIdx.x;        // 0..511

    // ---- stage x[b, :, c0:c0+NC] transposed (float2 global, b32 LDS scatter) ----
    {
        const int slot = tid & 15;       // float2 slot (16 per row)
        const int r0   = tid >> 4;       // 0..31
        const int col  = 2 * slot;
        const int csrc = (col + 1 < NC) ? col : (NC - 2);
        const float* base = x + ((size_t)b * LL) * CC + c0 + csrc;
        float* d0 = sxT + col * RS;
        float* d1 = sxT + (col + 1) * RS;
        #pragma unroll
        for (int k = 0; k < 11; ++k) {
            const int r = r0 + 32 * k;
            if (r < LL) {
                const float2 v = *reinterpret_cast<const float2*>(base + (size_t)r * CC);
                d0[r] = v.x;
                d1[r] = v.y;
            }
        }
    }
    __syncthreads();

    const int cc = tid & 31;
    const int p  = (tid >> 5) & 7;
    const int h  = tid >> 8;             // 0 or 1
    const int c  = c0 + cc;
    const bool wrOK = (cc < NC);
    const int cl = wrOK ? c : (CC - 1);  // clamped for global loads

    float A0 = 0.f, A6 = 0.f;
    float Au[5] = {0.f, 0.f, 0.f, 0.f, 0.f};
    float Pv[5] = {0.f, 0.f, 0.f, 0.f, 0.f};
    float msum = 0.f;
    float sw = 0.f;                      // fallback only

    const int s0 = h * SH;
    const float* xrow = sxT + cc * RS + 12 * s0;

    #pragma unroll 2
    for (int i = 0; i < SH; ++i) {
        const int s = s0 + i;
        float wa, wp;
        if (TRANS) {
            const float2 w = *reinterpret_cast<const float2*>(
                wpk + 2 * ((size_t)(p * S_IN + s) * CC + cl));
            wa = w.x; wp = w.y;
        } else {
            wa = wA_raw[(size_t)(cl * S_OUT + p) * S_IN + s];
            wp = wP_raw[(size_t)(cl * S_OUT + p) * S_IN + s];
            sw += wa;
        }
        const float4 xa = *reinterpret_cast<const float4*>(xrow + 12 * i);      // t0..3
        const float4 xb = *reinterpret_cast<const float4*>(xrow + 12 * i + 4);  // t4..7
        const float4 xc = *reinterpret_cast<const float4*>(xrow + 12 * i + 8);  // t8..11

        const float u1 = xa.y + xc.w;
        const float u2 = xa.z + xc.z;
        const float u3 = xa.w + xc.y;
        const float u4 = xb.x + xc.x;
        const float u5 = xb.y + xb.w;
        const float v1 = xa.y - xc.w;
        const float v2 = xa.z - xc.z;
        const float v3 = xa.w - xc.y;
        const float v4 = xb.x - xc.x;
        const float v5 = xb.y - xb.w;

        A0 = fmaf(wa, xa.x, A0);
        A6 = fmaf(wa, xb.z, A6);
        Au[0] = fmaf(wa, u1, Au[0]);
        Au[1] = fmaf(wa, u2, Au[1]);
        Au[2] = fmaf(wa, u3, Au[2]);
        Au[3] = fmaf(wa, u4, Au[3]);
        Au[4] = fmaf(wa, u5, Au[4]);
        Pv[0] = fmaf(wp, v1, Pv[0]);
        Pv[1] = fmaf(wp, v2, Pv[1]);
        Pv[2] = fmaf(wp, v3, Pv[2]);
        Pv[3] = fmaf(wp, v4, Pv[3]);
        Pv[4] = fmaf(wp, v5, Pv[4]);

        msum += (xa.x + xb.z) + ((u1 + u2) + (u3 + u4) + u5);
    }

    // ---- combine halves via LDS (overlaid on the dead x tile) ----
    __syncthreads();                     // all reads of sxT done
    float* red = sxT;                    // 256 * 14 floats = 14336 B
    if (h == 1) {
        float* r = red + (p * 32 + cc) * 14;
        r[0] = A0;  r[1] = A6;
        r[2] = Au[0]; r[3] = Au[1]; r[4] = Au[2]; r[5] = Au[3]; r[6] = Au[4];
        r[7] = Pv[0]; r[8] = Pv[1]; r[9] = Pv[2]; r[10] = Pv[3]; r[11] = Pv[4];
        r[12] = msum; r[13] = sw;
    }
    __syncthreads();
    if (h == 1) return;

    {
        const float* r = red + (p * 32 + cc) * 14;
        A0 += r[0];  A6 += r[1];
        Au[0] += r[2]; Au[1] += r[3]; Au[2] += r[4]; Au[3] += r[5]; Au[4] += r[6];
        Pv[0] += r[7]; Pv[1] += r[8]; Pv[2] += r[9]; Pv[3] += r[10]; Pv[4] += r[11];
        msum += r[12]; sw += r[13];
    }

    if (!wrOK) return;

    const float mean = msum * (1.0f / LL);

    float mc, bias[12];
    if (TRANS) {
        mc = mcoefT[p * CC + c];
        #pragma unroll
        for (int t = 0; t < 12; ++t) bias[t] = biasv[(size_t)(t * S_OUT + p) * CC + c];
    } else {
        mc = 1.0f - sw;
        const float ba = bAr[c * S_OUT + p], bp = bPr[c * S_OUT + p];
        #pragma unroll
        for (int t = 0; t < 12; ++t) {
            bias[t] = COEFP[t] * bp + (t == 0 ? SQRT12F * ba : 0.f);
        }
    }

    const float mb = mean * mc;
    float* ob = out + ((size_t)b * PRED + p * WIN) * CC + c;

    ob[0]               = A0 + mb + bias[0];
    ob[(size_t)6 * CC]  = A6 + mb + bias[6];
    #pragma unroll
    for (int t = 1; t <= 5; ++t) {
        ob[(size_t)t * CC]        = 0.5f * (Au[t-1] + Pv[t-1]) + mb + bias[t];
        ob[(size_t)(12 - t) * CC] = 0.5f * (Au[t-1] - Pv[t-1]) + mb + bias[12 - t];
    }
}

extern "C" void kernel_launch(void* const* d_in, const int* in_sizes, int n_in,
                              void* d_out, int out_size, void* d_ws, size_t ws_size,
                              hipStream_t stream) {
    const float* x  = (const float*)d_in[0];
    const float* wA = (const float*)d_in[1];
    const float* bA = (const float*)d_in[2];
    const float* wP = (const float*)d_in[3];
    const float* bP = (const float*)d_in[4];
    float* out = (float*)d_out;

    const size_t nW  = (size_t)S_OUT * S_IN * CC;    // 193088
    const size_t nM  = (size_t)S_OUT * CC;           // 6896
    const size_t nBv = (size_t)12 * S_OUT * CC;      // 82752
    const size_t need = (2 * nW + nM + nBv) * sizeof(float);

    dim3 grid(NTILES, BB);

    if (ws_size >= need) {
        float* wpk    = (float*)d_ws;                // 2*nW floats
        float* mcoefT = wpk + 2 * nW;
        float* biasv  = mcoefT + nM;

        prep_wpk<<<(int)((nW + 255) / 256), 256, 0, stream>>>(wA, wP, wpk);
        prep_mcoef<<<(int)((nM + 255) / 256), 256, 0, stream>>>(wA, mcoefT);
        prep_bias<<<(int)((nBv + 255) / 256), 256, 0, stream>>>(bA, bP, biasv);

        fused14<true><<<grid, 512, 0, stream>>>(
            x, wpk, mcoefT, biasv,
            nullptr, nullptr, nullptr, nullptr, out);
    } else {
        fused14<false><<<grid, 512, 0, stream>>>(
            x, nullptr, nullptr, nullptr,
            wA, wP, bA, bP, out);
    }
}